// Round 1
// baseline (549.675 us; speedup 1.0000x reference)
//
#include <hip/hip_runtime.h>
#include <math.h>

#define T_LEN   16000
#define THREADS 256
#define CHUNK   63      // 256*63 = 16128 >= 16000; odd stride -> no LDS bank conflicts
#define EPS_F   1e-6f

__launch_bounds__(THREADS)
__global__ void pcen_kernel(const float* __restrict__ x,
                            const float* __restrict__ alpha,
                            const float* __restrict__ delta,
                            const float* __restrict__ root,
                            const float* __restrict__ ema_w,
                            float* __restrict__ out, int C) {
    __shared__ __align__(16) float buf[T_LEN];
    __shared__ float swA[4], swB[4];

    const int row = blockIdx.x;
    const int c   = row % C;
    const int tid = threadIdx.x;

    const float s   = fminf(fmaxf(ema_w[c], 0.0f), 1.0f);
    const float q   = 1.0f - s;
    const float a_c = fminf(alpha[c], 1.0f);
    const float r   = 1.0f / fmaxf(root[c], 1.0f);
    const float d   = delta[c];
    const float dr  = powf(d, r);

    const float* xr   = x   + (size_t)row * T_LEN;
    float*       outr = out + (size_t)row * T_LEN;

    // ---- coalesced global -> LDS stage (float4) ----
    const float4* x4 = (const float4*)xr;
    float4*       b4 = (float4*)buf;
    for (int i = tid; i < T_LEN / 4; i += THREADS) b4[i] = x4[i];
    __syncthreads();

    // ---- pass 1: per-thread local (A,b) composition over chunk ----
    const int base = tid * CHUNK;
    const int end  = min(base + CHUNK, T_LEN);
    float a = 1.0f, b = 0.0f;
    for (int g = base; g < end; ++g) {
        float xv = buf[g];
        float xa = (g == 0) ? 0.0f : q;
        float xb = (g == 0) ? xv   : s * xv;
        b = fmaf(xa, b, xb);
        a *= xa;
    }

    // ---- wave-level inclusive scan (Hillis-Steele over 64 lanes) ----
    const int lane = tid & 63;
    const int wave = tid >> 6;
    float la = a, lb = b;
    #pragma unroll
    for (int off = 1; off < 64; off <<= 1) {
        float ua = __shfl_up(la, off);
        float ub = __shfl_up(lb, off);
        if (lane >= off) {
            lb = fmaf(la, ub, lb);   // combine(earlier=(ua,ub), later=(la,lb))
            la *= ua;
        }
    }

    // ---- cross-wave combine via LDS ----
    if (lane == 63) { swA[wave] = la; swB[wave] = lb; }
    __syncthreads();
    float pb = 0.0f;                 // exclusive wave prefix (b only is needed)
    #pragma unroll
    for (int w = 0; w < 3; ++w) {
        if (w < wave) pb = fmaf(swA[w], pb, swB[w]);
    }

    // ---- exclusive prefix for this thread -> incoming EMA state ----
    float ea = __shfl_up(la, 1);
    float eb = __shfl_up(lb, 1);
    float e_in = (lane == 0) ? pb : fmaf(ea, pb, eb);

    // ---- pass 2: recompute EMA with true prefix + pointwise output ----
    float e = e_in;
    for (int g = base; g < end; ++g) {
        float xv = buf[g];
        e = (g == 0) ? xv : fmaf(q, e, s * xv);
        float t  = exp2f(a_c * log2f(EPS_F + e));     // (EPS+ema)^alpha
        float o  = exp2f(r * log2f(xv / t + d)) - dr; // (x/t + d)^r - d^r
        buf[g] = o;
    }
    __syncthreads();

    // ---- coalesced LDS -> global store (float4) ----
    float4* o4 = (float4*)outr;
    for (int i = tid; i < T_LEN / 4; i += THREADS) o4[i] = b4[i];
}

extern "C" void kernel_launch(void* const* d_in, const int* in_sizes, int n_in,
                              void* d_out, int out_size, void* d_ws, size_t ws_size,
                              hipStream_t stream) {
    const float* x     = (const float*)d_in[0];
    const float* alpha = (const float*)d_in[1];
    const float* delta = (const float*)d_in[2];
    const float* root  = (const float*)d_in[3];
    const float* ema_w = (const float*)d_in[4];
    float* out = (float*)d_out;

    const int C    = in_sizes[1];               // 128
    const int rows = in_sizes[0] / T_LEN;       // B*C = 4096

    pcen_kernel<<<rows, THREADS, 0, stream>>>(x, alpha, delta, root, ema_w, out, C);
}

// Round 2
// 453.019 us; speedup vs baseline: 1.2134x; 1.2134x over previous
//
#include <hip/hip_runtime.h>
#include <math.h>

#define T_LEN    16000
#define T_LEN4   4000          // float4 count per row
#define THREADS  256
#define CHUNK    17            // odd -> stride-17 LDS access, conflict-free
#define TILE     (THREADS * CHUNK)   // 4352 floats = 17408 B
#define TILE4    (TILE / 4)          // 1088 float4
#define NT       4             // 4 * 4352 = 17408 >= 16000
#define EPS_F    1e-6f

__launch_bounds__(THREADS, 4)   // 4 waves/EU -> 16 waves/CU -> caps VGPR at 128
__global__ void pcen_kernel(const float* __restrict__ x,
                            const float* __restrict__ alpha,
                            const float* __restrict__ delta,
                            const float* __restrict__ root,
                            const float* __restrict__ ema_w,
                            float* __restrict__ out, int C) {
    __shared__ __align__(16) float buf[TILE];
    __shared__ float swA[4], swB[4];

    const int row  = blockIdx.x;
    const int c    = row % C;
    const int tid  = threadIdx.x;
    const int lane = tid & 63;
    const int wave = tid >> 6;

    const float s   = fminf(fmaxf(ema_w[c], 0.0f), 1.0f);
    const float q   = 1.0f - s;
    const float a_c = fminf(alpha[c], 1.0f);
    const float r   = 1.0f / fmaxf(root[c], 1.0f);
    const float d   = delta[c];
    const float dr  = powf(d, r);

    const float4* x4 = (const float4*)(x   + (size_t)row * T_LEN);
    float4*       o4 = (float4*)      (out + (size_t)row * T_LEN);
    float4*       b4 = (float4*)buf;

    float e_carry = 0.0f;
    const int lbase = tid * CHUNK;

    for (int t = 0; t < NT; ++t) {
        const int tb4 = t * TILE4;

        // ---- stage: global -> LDS, coalesced float4, linear layout ----
        #pragma unroll
        for (int k = 0; k < 5; ++k) {
            int i4l = tid + k * THREADS;
            if (i4l < TILE4) {
                int i4 = tb4 + i4l;
                b4[i4l] = (i4 < T_LEN4) ? x4[i4] : make_float4(1.f, 1.f, 1.f, 1.f);
            }
        }
        __syncthreads();

        // ---- pass 1: per-thread (A,b) composition over 17 elements ----
        float a = 1.0f, b = 0.0f;
        #pragma unroll
        for (int j = 0; j < CHUNK; ++j) {
            float xv = buf[lbase + j];
            bool first = (t == 0) & (tid == 0) & (j == 0);
            float xa = first ? 0.0f : q;
            float xb = first ? xv   : s * xv;
            b = fmaf(xa, b, xb);
            a *= xa;
        }

        // ---- wave-level inclusive scan (Hillis-Steele, 64 lanes) ----
        float la = a, lb = b;
        #pragma unroll
        for (int off = 1; off < 64; off <<= 1) {
            float ua = __shfl_up(la, off);
            float ub = __shfl_up(lb, off);
            if (lane >= off) { lb = fmaf(la, ub, lb); la *= ua; }
        }
        if (lane == 63) { swA[wave] = la; swB[wave] = lb; }
        __syncthreads();

        // ---- wave-exclusive prefix pair (pa, pb) ----
        float pa = 1.0f, pb = 0.0f;
        #pragma unroll
        for (int w = 0; w < 3; ++w) {
            if (w < wave) { pb = fmaf(swA[w], pb, swB[w]); pa *= swA[w]; }
        }
        // ---- thread-exclusive prefix within wave ----
        float ea = __shfl_up(la, 1);
        float eb = __shfl_up(lb, 1);
        float a_ex, b_ex;
        if (lane == 0) { a_ex = pa;      b_ex = pb; }
        else           { a_ex = pa * ea; b_ex = fmaf(ea, pb, eb); }
        float e = fmaf(a_ex, e_carry, b_ex);   // EMA state entering this chunk

        // ---- tile-total -> carry for next tile (uniform across threads) ----
        float ta = 1.0f, tb = 0.0f;
        #pragma unroll
        for (int w = 0; w < 4; ++w) { tb = fmaf(swA[w], tb, swB[w]); ta *= swA[w]; }
        e_carry = fmaf(ta, e_carry, tb);

        // ---- pass 2: recompute EMA + pointwise (log-space, no divide) ----
        #pragma unroll
        for (int j = 0; j < CHUNK; ++j) {
            float xv = buf[lbase + j];
            bool first = (t == 0) & (tid == 0) & (j == 0);
            e = first ? xv : fmaf(q, e, s * xv);
            float lge = log2f(EPS_F + e);
            float lgx = log2f(xv);
            float v   = exp2f(fmaf(-a_c, lge, lgx));     // x / (eps+e)^alpha
            float o   = exp2f(r * log2f(v + d)) - dr;    // (v+d)^r - d^r
            buf[lbase + j] = o;
        }
        __syncthreads();

        // ---- store: LDS -> global, coalesced float4 ----
        #pragma unroll
        for (int k = 0; k < 5; ++k) {
            int i4l = tid + k * THREADS;
            if (i4l < TILE4) {
                int i4 = tb4 + i4l;
                if (i4 < T_LEN4) o4[i4] = b4[i4l];
            }
        }
        __syncthreads();   // protect buf/swA/swB before next tile overwrites
    }
}

extern "C" void kernel_launch(void* const* d_in, const int* in_sizes, int n_in,
                              void* d_out, int out_size, void* d_ws, size_t ws_size,
                              hipStream_t stream) {
    const float* x     = (const float*)d_in[0];
    const float* alpha = (const float*)d_in[1];
    const float* delta = (const float*)d_in[2];
    const float* root  = (const float*)d_in[3];
    const float* ema_w = (const float*)d_in[4];
    float* out = (float*)d_out;

    const int C    = in_sizes[1];               // 128
    const int rows = in_sizes[0] / T_LEN;       // B*C = 4096

    pcen_kernel<<<rows, THREADS, 0, stream>>>(x, alpha, delta, root, ema_w, out, C);
}